// Round 1
// baseline (145.030 us; speedup 1.0000x reference)
//
#include <hip/hip_runtime.h>

// OccupancyGridForestAS: per-point voxel lookup in a forest of 64 dense 64^3 grids,
// addressed via an 8^3 block->tree lookup table.
//
// Inputs (setup_inputs order):
//   d_in[0]: pts            float32 [4194304, 3]   (48 MiB, streamed)
//   d_in[1]: occ_val_grid   float32 [64, 64, 64, 64] (64 MiB, random 4B gathers)
//   d_in[2]: block_lookup   int32   [8, 8, 8]      (2 KiB)
// Output: float32 [4194304] (16 MiB, streamed)
//
// R3 -> R4 changes (theory: prefetch is the bottleneck under BOTH candidate models):
//  * DROP the full-grid L3 prefetch. Only 64/512 block cells are valid -> only
//    12.5% of points gather; gathers touch ~39% of grid lines (~26 MB unique).
//    The prefetch streamed 64 MB (plus up to 64 MB of dirty-poison MALL victim
//    writebacks, invisible to WRITE_SIZE) to convert 26 MB of gathers into L3
//    hits -- a net bus loss. It ALSO serialized each wave into three dependent
//    HBM round trips (pf-accumulate waits + the vmcnt(0) drain at the barrier).
//  * __syncthreads() moved BEFORE any global load: the barrier's mandatory
//    s_waitcnt vmcnt(0) drain now costs nothing.
//  * pts loads / out stores are nontemporal (streamed once, never reused):
//    avoids MALL allocation -> no poison-eviction writebacks for the 64 MB of
//    pure streams. Gathers stay cacheable (grid[0] broadcast line + ~10%
//    multi-hit lines benefit).
//  * Latency hiding for the random gathers: 8 independent gathers/thread,
//    32 waves/CU -> hundreds of outstanding lines per CU.

#define LDIM 8
#define RES  64
#define PPT  8   // points per thread

typedef float v4f __attribute__((ext_vector_type(4)));

__global__ __launch_bounds__(256, 8) void occ_forest_kernel(
    const v4f*    __restrict__ pts4,
    const float*  __restrict__ grid,
    const int*    __restrict__ lookup,
    v4f*          __restrict__ out4,
    int n8)       // number of 8-point groups (= total threads)
{
    __shared__ int slut[LDIM * LDIM * LDIM];  // 512 ints = 2 KB

    // Stage lookup table into LDS (coalesced int2 loads).
    {
        const int2* lk2 = (const int2*)lookup;
        int2* sl2 = (int2*)slut;
        sl2[threadIdx.x] = lk2[threadIdx.x];  // 256 threads x 8B = 2 KB
    }
    // Barrier BEFORE any global load: its vmcnt(0)+lgkmcnt(0) drain only waits
    // on the 8B LDS store above (trivial), not on in-flight HBM loads.
    __syncthreads();

    int j = blockIdx.x * blockDim.x + threadIdx.x;

    // 8 points = 24 floats = 6 float4s, fully coalesced, nontemporal (read-once).
    const v4f* p = pts4 + 6 * j;
    v4f q0 = __builtin_nontemporal_load(p + 0);
    v4f q1 = __builtin_nontemporal_load(p + 1);
    v4f q2 = __builtin_nontemporal_load(p + 2);
    v4f q3 = __builtin_nontemporal_load(p + 3);
    v4f q4 = __builtin_nontemporal_load(p + 4);
    v4f q5 = __builtin_nontemporal_load(p + 5);

    float px[PPT] = {q0.x, q0.w, q1.z, q2.y, q3.x, q3.w, q4.z, q5.y};
    float py[PPT] = {q0.y, q1.x, q1.w, q2.z, q3.y, q4.x, q4.w, q5.z};
    float pz[PPT] = {q0.z, q1.y, q2.x, q2.w, q3.z, q4.y, q5.x, q5.w};

    int  idx[PPT];
    bool valid[PPT];

    // Phase 1: pure ALU -- compute all gather indices (0 for invalid lanes so
    // they coalesce into a single broadcast line hit).
#pragma unroll
    for (int k = 0; k < PPT; ++k) {
        float x = px[k], y = py[k], z = pz[k];

        int bx = (int)floorf(x);
        int by = (int)floorf(y);
        int bz = (int)floorf(z);
        bool in_dom = (bx >= 0) & (bx < LDIM) &
                      (by >= 0) & (by < LDIM) &
                      (bz >= 0) & (bz < LDIM);
        int cx = min(max(bx, 0), LDIM - 1);
        int cy = min(max(by, 0), LDIM - 1);
        int cz = min(max(bz, 0), LDIM - 1);

        int bidx = slut[(cx * LDIM + cy) * LDIM + cz];
        bool v = in_dom & (bidx >= 0);

        // Reference float op sequence, replicated exactly:
        // block_x = 2*(p - bcs) - 1 ; t = (block_x*0.5 + 0.5)*res ; vox = clip(floor(t),0,res-1)
        float bxf = 2.0f * (x - (float)cx) - 1.0f;
        float byf = 2.0f * (y - (float)cy) - 1.0f;
        float bzf = 2.0f * (z - (float)cz) - 1.0f;
        float tx = (bxf * 0.5f + 0.5f) * (float)RES;
        float ty = (byf * 0.5f + 0.5f) * (float)RES;
        float tz = (bzf * 0.5f + 0.5f) * (float)RES;
        int vx = min(max((int)floorf(tx), 0), RES - 1);
        int vy = min(max((int)floorf(ty), 0), RES - 1);
        int vz = min(max((int)floorf(tz), 0), RES - 1);

        int sb = v ? bidx : 0;
        int ii = ((sb * RES + vx) * RES + vy) * RES + vz;  // < 2^24
        idx[k]   = v ? ii : 0;   // invalid -> grid[0]: same-line broadcast, ~free
        valid[k] = v;
    }

    // Phase 2: 8 independent unconditional gathers -- all in flight at once.
    // These are cacheable (not nt): grid[0] broadcast line stays in L1, and
    // ~10% of gathered lines are hit more than once.
    float vals[PPT];
#pragma unroll
    for (int k = 0; k < PPT; ++k) {
        vals[k] = grid[idx[k]];
    }

    // Phase 3: select + coalesced nontemporal store.
#pragma unroll
    for (int k = 0; k < PPT; ++k) {
        vals[k] = valid[k] ? vals[k] : 0.0f;
    }

    v4f o0 = {vals[0], vals[1], vals[2], vals[3]};
    v4f o1 = {vals[4], vals[5], vals[6], vals[7]};
    __builtin_nontemporal_store(o0, out4 + 2 * j + 0);
    __builtin_nontemporal_store(o1, out4 + 2 * j + 1);
}

extern "C" void kernel_launch(void* const* d_in, const int* in_sizes, int n_in,
                              void* d_out, int out_size, void* d_ws, size_t ws_size,
                              hipStream_t stream) {
    const float* pts    = (const float*)d_in[0];
    const float* grid   = (const float*)d_in[1];
    const int*   lookup = (const int*)d_in[2];
    float*       out    = (float*)d_out;

    // out_size = 4194304, divisible by 8; 8 points per thread.
    int n8 = out_size / PPT;                    // 524288 threads
    int threads = 256;
    int blocks = (n8 + threads - 1) / threads;  // 2048 blocks = 8/CU, all co-resident
    occ_forest_kernel<<<blocks, threads, 0, stream>>>(
        (const v4f*)pts, grid, lookup, (v4f*)out, n8);
}

// Round 2
// 144.049 us; speedup vs baseline: 1.0068x; 1.0068x over previous
//
#include <hip/hip_runtime.h>

// OccupancyGridForestAS: per-point voxel lookup in a forest of 64 dense 64^3 grids,
// addressed via an 8^3 block->tree lookup table.
//
// Inputs (setup_inputs order):
//   d_in[0]: pts            float32 [4194304, 3]   (48 MiB, streamed)
//   d_in[1]: occ_val_grid   float32 [64, 64, 64, 64] (64 MiB, random 4B gathers)
//   d_in[2]: block_lookup   int32   [8, 8, 8]      (2 KiB)
// Output: float32 [4194304] (16 MiB, streamed)
//
// R4 -> R5 (post-mortem of R4): removing the grid prefetch REGRESSED the
// cold-cache time (timed-region arithmetic: ~42.6 -> ~45 us/launch; the
// profiled replays only looked faster because rocprof replay leaves grid
// warm in L3). R0 counters (2.55 TB/s at 106 MB traffic) show the kernel is
// random-access-efficiency bound, not BW-bound: converting ~26 MB of random
// gathers into a 64 MB sequential sweep + L3 hits is a net win.
//
// R5 therefore recombines:
//  * Full 64 MB grid sweep restored, but FIRE-AND-FORGET via
//    __builtin_amdgcn_global_load_lds into a scratch LDS buffer that is never
//    read and never waited on. R0 consumed the prefetch (pf accumulator) ->
//    full vmcnt drain serialized it into every wave's critical path. Now the
//    ALU phase waits only on the 6 pts loads (vmcnt(8)); the sweep streams
//    concurrently, warming L3 for the gathers.
//  * Early __syncthreads() (before any global load) kept from R4: barrier's
//    mandatory vmcnt(0) drain costs nothing.
//  * Nontemporal pts loads / out stores kept from R4: 64 MB of pure streams
//    don't evict grid lines from the 256 MB L3 (synergy with the sweep).

#define LDIM 8
#define RES  64
#define PPT  8   // points per thread
#define PF_ITERS 8  // 8 x 16B x 524288 threads = 64 MiB = whole grid

typedef float v4f __attribute__((ext_vector_type(4)));

__global__ __launch_bounds__(256, 8) void occ_forest_kernel(
    const v4f*    __restrict__ pts4,
    const float*  __restrict__ grid,
    const int*    __restrict__ lookup,
    v4f*          __restrict__ out4,
    int n8)       // number of 8-point groups (= total threads)
{
    __shared__ int   slut[LDIM * LDIM * LDIM];  // 512 ints = 2 KB
    __shared__ float pfscratch[256];            // 1 KB sink for the L3 sweep (never read)

    // Stage lookup table into LDS (coalesced int2 loads).
    {
        const int2* lk2 = (const int2*)lookup;
        int2* sl2 = (int2*)slut;
        sl2[threadIdx.x] = lk2[threadIdx.x];  // 256 threads x 8B = 2 KB
    }
    // Barrier BEFORE any global load: its vmcnt(0)+lgkmcnt(0) drain only waits
    // on the 8B LDS store above (trivial), not on in-flight HBM loads.
    __syncthreads();

    int j = blockIdx.x * blockDim.x + threadIdx.x;

    // 8 points = 24 floats = 6 float4s, fully coalesced, nontemporal (read-once).
    // Issued FIRST so the ALU phase's waitcnt covers only these (vmcnt(8)).
    const v4f* p = pts4 + 6 * j;
    v4f q0 = __builtin_nontemporal_load(p + 0);
    v4f q1 = __builtin_nontemporal_load(p + 1);
    v4f q2 = __builtin_nontemporal_load(p + 2);
    v4f q3 = __builtin_nontemporal_load(p + 3);
    v4f q4 = __builtin_nontemporal_load(p + 4);
    v4f q5 = __builtin_nontemporal_load(p + 5);

    // --- Fire-and-forget L3 sweep of the grid: 8 coalesced 16B global->LDS
    // loads per thread, all waves dumping into the same 1 KB scratch (races
    // are harmless; the data is never read). No VGPR round-trip, no waitcnt
    // consumer -> never on the critical path. Total coverage: 64 MiB.
    {
        const float* gbase = grid + 4 * j;        // 16B per thread, coalesced
        const int    stride = 4 * n8;             // floats per sweep iteration
#pragma unroll
        for (int s = 0; s < PF_ITERS; ++s) {
            __builtin_amdgcn_global_load_lds(
                (const __attribute__((address_space(1))) void*)(gbase + s * stride),
                (__attribute__((address_space(3))) void*)pfscratch,
                16, 0, 0);
        }
    }

    float px[PPT] = {q0.x, q0.w, q1.z, q2.y, q3.x, q3.w, q4.z, q5.y};
    float py[PPT] = {q0.y, q1.x, q1.w, q2.z, q3.y, q4.x, q4.w, q5.z};
    float pz[PPT] = {q0.z, q1.y, q2.x, q2.w, q3.z, q4.y, q5.x, q5.w};

    int  idx[PPT];
    bool valid[PPT];

    // Phase 1: pure ALU -- compute all gather indices (0 for invalid lanes so
    // they coalesce into a single broadcast line hit).
#pragma unroll
    for (int k = 0; k < PPT; ++k) {
        float x = px[k], y = py[k], z = pz[k];

        int bx = (int)floorf(x);
        int by = (int)floorf(y);
        int bz = (int)floorf(z);
        bool in_dom = (bx >= 0) & (bx < LDIM) &
                      (by >= 0) & (by < LDIM) &
                      (bz >= 0) & (bz < LDIM);
        int cx = min(max(bx, 0), LDIM - 1);
        int cy = min(max(by, 0), LDIM - 1);
        int cz = min(max(bz, 0), LDIM - 1);

        int bidx = slut[(cx * LDIM + cy) * LDIM + cz];
        bool v = in_dom & (bidx >= 0);

        // Reference float op sequence, replicated exactly:
        // block_x = 2*(p - bcs) - 1 ; t = (block_x*0.5 + 0.5)*res ; vox = clip(floor(t),0,res-1)
        float bxf = 2.0f * (x - (float)cx) - 1.0f;
        float byf = 2.0f * (y - (float)cy) - 1.0f;
        float bzf = 2.0f * (z - (float)cz) - 1.0f;
        float tx = (bxf * 0.5f + 0.5f) * (float)RES;
        float ty = (byf * 0.5f + 0.5f) * (float)RES;
        float tz = (bzf * 0.5f + 0.5f) * (float)RES;
        int vx = min(max((int)floorf(tx), 0), RES - 1);
        int vy = min(max((int)floorf(ty), 0), RES - 1);
        int vz = min(max((int)floorf(tz), 0), RES - 1);

        int sb = v ? bidx : 0;
        int ii = ((sb * RES + vx) * RES + vy) * RES + vz;  // < 2^24
        idx[k]   = v ? ii : 0;   // invalid -> grid[0]: same-line broadcast, ~free
        valid[k] = v;
    }

    // Phase 2: 8 independent unconditional gathers -- all in flight at once.
    // Cacheable: mostly L3 hits once the sweep has passed the line.
    float vals[PPT];
#pragma unroll
    for (int k = 0; k < PPT; ++k) {
        vals[k] = grid[idx[k]];
    }

    // Phase 3: select + coalesced nontemporal store.
#pragma unroll
    for (int k = 0; k < PPT; ++k) {
        vals[k] = valid[k] ? vals[k] : 0.0f;
    }

    v4f o0 = {vals[0], vals[1], vals[2], vals[3]};
    v4f o1 = {vals[4], vals[5], vals[6], vals[7]};
    __builtin_nontemporal_store(o0, out4 + 2 * j + 0);
    __builtin_nontemporal_store(o1, out4 + 2 * j + 1);
}

extern "C" void kernel_launch(void* const* d_in, const int* in_sizes, int n_in,
                              void* d_out, int out_size, void* d_ws, size_t ws_size,
                              hipStream_t stream) {
    const float* pts    = (const float*)d_in[0];
    const float* grid   = (const float*)d_in[1];
    const int*   lookup = (const int*)d_in[2];
    float*       out    = (float*)d_out;

    // out_size = 4194304, divisible by 8; 8 points per thread.
    int n8 = out_size / PPT;                    // 524288 threads
    int threads = 256;
    int blocks = (n8 + threads - 1) / threads;  // 2048 blocks = 8/CU, all co-resident
    occ_forest_kernel<<<blocks, threads, 0, stream>>>(
        (const v4f*)pts, grid, lookup, (v4f*)out, n8);
}